// Round 1
// baseline (467.958 us; speedup 1.0000x reference)
//
#include <hip/hip_runtime.h>
#include <hip/hip_bf16.h>
#include <math.h>

#define NE 80000
#define NN 10000
#define NG 16
#define MP_NORM 0.31622776601683794f   // 1/sqrt(10)
#define RBF_NORM 0.60302268915552724f  // sqrt(2/5.5)

// monomial tables: index -> (lx,ly,lz), l
__constant__ int c_mx[20] = {0, 1,0,0, 2,1,1,0,0,0, 3,2,2,1,1,1,0,0,0,0};
__constant__ int c_my[20] = {0, 0,1,0, 0,1,0,2,1,0, 0,1,0,2,1,0,3,2,1,0};
__constant__ int c_mz[20] = {0, 0,0,1, 0,0,1,0,1,2, 0,0,1,0,1,2,0,1,2,3};

__device__ __forceinline__ int l_of_a(int a) {
    return (a >= 10) ? 3 : ((a >= 4) ? 2 : ((a >= 1) ? 1 : 0));
}

// ---------------------------------------------------------------------------
// Pass 1: per-edge featurization, fold W_rt into the radial vector, scatter
// A[n,s,a,c] (+= radt[l_a,s]*ang[a]*code[c]) via atomics. One wave per edge.
// ---------------------------------------------------------------------------
__global__ __launch_bounds__(256) void k_edge1(
    const float* __restrict__ pos, const int* __restrict__ ntype,
    const int* __restrict__ src, const int* __restrict__ dst,
    const float* __restrict__ shifts, const float* __restrict__ Wemb,
    const float* __restrict__ freqs, const float* __restrict__ W_rt,
    float* __restrict__ A)
{
    __shared__ float sh[4][56];   // per wave: ang[0..19], code[20..28], radt[29..52]
    const int wave = threadIdx.x >> 6, lane = threadIdx.x & 63;
    const int e = blockIdx.x * 4 + wave;
    float* S = sh[wave];
    float fc = 0.f;
    int dn = 0;
    if (e < NE) {
        const int sn = src[e];
        dn = dst[e];
        const float vx = pos[3*dn+0] - pos[3*sn+0] + shifts[3*e+0];
        const float vy = pos[3*dn+1] - pos[3*sn+1] + shifts[3*e+1];
        const float vz = pos[3*dn+2] - pos[3*sn+2] + shifts[3*e+2];
        const float r = sqrtf(vx*vx + vy*vy + vz*vz) + 1e-9f;
        const float u = r * (1.0f / 5.5f);
        if (u < 1.0f) {
            const float u2 = u*u, u3 = u2*u, u6 = u3*u3;
            fc = 1.0f - 28.0f*u6 + 48.0f*u6*u - 21.0f*u6*u2;
            const float inv = 1.0f / r;
            const float ux = vx*inv, uy = vy*inv, uz = vz*inv;
            float rb[6];
            #pragma unroll
            for (int k = 0; k < 6; k++)
                rb[k] = RBF_NORM * sinf(r * freqs[k]) * inv * fc;
            if (lane < 20) {
                const int lx = c_mx[lane], ly = c_my[lane], lz = c_mz[lane];
                float v = 1.f;
                for (int i = 0; i < lx; i++) v *= ux;
                for (int i = 0; i < ly; i++) v *= uy;
                for (int i = 0; i < lz; i++) v *= uz;
                S[lane] = v;
            } else if (lane < 29) {
                const int c = lane - 20;
                S[lane] = Wemb[3*ntype[sn] + c/3] * Wemb[3*ntype[dn] + c%3];
            } else if (lane >= 32 && lane < 56) {
                const int j = lane - 32, l = j / 6, s2 = j % 6;
                float acc = 0.f;
                #pragma unroll
                for (int r2 = 0; r2 < 6; r2++)
                    acc += rb[r2] * W_rt[(l*6 + r2)*6 + s2];
                S[29 + j] = acc;
            }
        }
    }
    __syncthreads();
    if (e < NE && fc != 0.f) {
        float* base = A + (long)dn * 1080;
        for (int i = lane; i < 1080; i += 64) {
            const int s2 = i / 180, rem = i - s2*180;
            const int a = rem / 9, c = rem - a*9;
            const float val = S[29 + l_of_a(a)*6 + s2] * S[a] * S[20 + c];
            atomicAdd(base + i, val);
        }
    }
}

// ---------------------------------------------------------------------------
// Pass 2: scatter both messages in one atomic stream:
// Q[dst,s,a,c] += radtB[l,s]*ang[a]*code[c]*chi[src,c] + A[src,s,a,c]*radtA[l,s]
// ---------------------------------------------------------------------------
__global__ __launch_bounds__(256) void k_edge2(
    const float* __restrict__ pos, const int* __restrict__ ntype,
    const int* __restrict__ src, const int* __restrict__ dst,
    const float* __restrict__ shifts, const float* __restrict__ Wemb,
    const float* __restrict__ freqs, const float* __restrict__ W_rt,
    const float* __restrict__ W_Ar, const float* __restrict__ chi,
    const float* __restrict__ A, float* __restrict__ Q)
{
    __shared__ float sh[4][80];   // ang[0..19], codechi[20..28], radtB[29..52], radtA[53..76]
    const int wave = threadIdx.x >> 6, lane = threadIdx.x & 63;
    const int e = blockIdx.x * 4 + wave;
    float* S = sh[wave];
    float fc = 0.f;
    int dn = 0, sn = 0;
    if (e < NE) {
        sn = src[e];
        dn = dst[e];
        const float vx = pos[3*dn+0] - pos[3*sn+0] + shifts[3*e+0];
        const float vy = pos[3*dn+1] - pos[3*sn+1] + shifts[3*e+1];
        const float vz = pos[3*dn+2] - pos[3*sn+2] + shifts[3*e+2];
        const float r = sqrtf(vx*vx + vy*vy + vz*vz) + 1e-9f;
        const float u = r * (1.0f / 5.5f);
        if (u < 1.0f) {
            const float u2 = u*u, u3 = u2*u, u6 = u3*u3;
            fc = 1.0f - 28.0f*u6 + 48.0f*u6*u - 21.0f*u6*u2;
            const float inv = 1.0f / r;
            const float ux = vx*inv, uy = vy*inv, uz = vz*inv;
            float rb[6];
            #pragma unroll
            for (int k = 0; k < 6; k++)
                rb[k] = RBF_NORM * sinf(r * freqs[k]) * inv * fc;
            if (lane < 20) {
                const int lx = c_mx[lane], ly = c_my[lane], lz = c_mz[lane];
                float v = 1.f;
                for (int i = 0; i < lx; i++) v *= ux;
                for (int i = 0; i < ly; i++) v *= uy;
                for (int i = 0; i < lz; i++) v *= uz;
                S[lane] = v;
            } else if (lane < 29) {
                const int c = lane - 20;
                S[lane] = Wemb[3*ntype[sn] + c/3] * Wemb[3*ntype[dn] + c%3]
                        * chi[sn*9 + c];
            } else if (lane >= 32 && lane < 56) {
                const int j = lane - 32, l = j / 6, s2 = j % 6;
                float accB = 0.f, accA = 0.f;
                #pragma unroll
                for (int r2 = 0; r2 < 6; r2++) {
                    accB += rb[r2] * W_rt[(l*6 + r2)*6 + s2];
                    accA += rb[r2] * W_Ar[(l*6 + r2)*6 + s2];
                }
                S[29 + j] = accB;
                S[53 + j] = accA;
            }
        }
    }
    __syncthreads();
    if (e < NE && fc != 0.f) {
        const float* asrc = A + (long)sn * 1080;
        float* base = Q + (long)dn * 1080;
        for (int i = lane; i < 1080; i += 64) {
            const int s2 = i / 180, rem = i - s2*180;
            const int a = rem / 9, c = rem - a*9;
            const int l6 = l_of_a(a)*6 + s2;
            const float val = S[29 + l6] * S[a] * S[20 + c] + asrc[i] * S[53 + l6];
            atomicAdd(base + i, val);
        }
    }
}

// ---------------------------------------------------------------------------
// Symmetrize: A[n,s,0..19,c] -> B[n,s,0..5,c]
// ---------------------------------------------------------------------------
__global__ __launch_bounds__(256) void k_symm(const float* __restrict__ A,
                                              float* __restrict__ B)
{
    const int t = blockIdx.x * 256 + threadIdx.x;
    if (t >= NN * 54) return;
    const int c = t % 9, s2 = (t / 9) % 6, n = t / 54;
    const float* a = A + (long)n*1080 + s2*180 + c;
    float v[20];
    #pragma unroll
    for (int i = 0; i < 20; i++) v[i] = a[i*9];
    const float o0 = v[0];
    const float o1 = v[1]*v[1] + v[2]*v[2] + v[3]*v[3];
    const float o2 = v[4]*v[4] + 2.f*v[5]*v[5] + 2.f*v[6]*v[6]
                   + v[7]*v[7] + 2.f*v[8]*v[8] + v[9]*v[9];
    const float o3 = v[10]*v[10] + 3.f*v[11]*v[11] + 3.f*v[12]*v[12]
                   + 3.f*v[13]*v[13] + 6.f*v[14]*v[14] + 3.f*v[15]*v[15]
                   + v[16]*v[16] + 3.f*v[17]*v[17] + 3.f*v[18]*v[18] + v[19]*v[19];
    const float o4 = v[1]*v[1]*v[4] + 2.f*v[1]*v[2]*v[5] + 2.f*v[1]*v[3]*v[6]
                   + 2.f*v[2]*v[1]*v[5] + v[2]*v[2]*v[7] + 2.f*v[2]*v[3]*v[8]
                   + 2.f*v[3]*v[1]*v[6] + 2.f*v[3]*v[2]*v[8] + v[3]*v[3]*v[9];
    const float o5 =
        v[1]*(v[4]*v[10] + 3.f*v[5]*v[11] + 3.f*v[6]*v[12] + 3.f*v[7]*v[13]
              + 6.f*v[8]*v[14] + 3.f*v[9]*v[15])
      + v[2]*(3.f*v[4]*v[11] + 3.f*v[5]*v[13] + 6.f*v[6]*v[14] + v[7]*v[16]
              + 3.f*v[8]*v[17] + 3.f*v[9]*v[18])
      + v[3]*(3.f*v[4]*v[12] + 6.f*v[5]*v[14] + 3.f*v[6]*v[15] + 3.f*v[7]*v[17]
              + 3.f*v[8]*v[18] + v[9]*v[19]);
    float* b = B + (long)n*324 + s2*54 + c;
    b[0]  = o0;
    b[9]  = o1;
    b[18] = o2;
    b[27] = o3;
    b[36] = o4;
    b[45] = o5;
}

// chi[n,c'] = B[n,:].W_chi[:,c']
__global__ __launch_bounds__(256) void k_chi(const float* __restrict__ B,
                                             const float* __restrict__ W_chi,
                                             float* __restrict__ chi)
{
    const int t = blockIdx.x * 256 + threadIdx.x;
    if (t >= NN * 9) return;
    const int cp = t % 9, n = t / 9;
    const float* b = B + (long)n * 324;
    float acc = 0.f;
    for (int j = 0; j < 324; j++) acc += b[j] * W_chi[j*9 + cp];
    chi[t] = acc;
}

// Q[n,s,a,c] = Q[n,s,a,c]*MP_NORM + sum_s' A[n,s',a,c]*W_mem[l_a,s',s]
__global__ __launch_bounds__(256) void k_comb(const float* __restrict__ A,
                                              const float* __restrict__ W_mem,
                                              float* __restrict__ Q)
{
    const int t = blockIdx.x * 256 + threadIdx.x;
    if (t >= NN * 180) return;
    const int c = t % 9, a = (t / 9) % 20, n = t / 180;
    const int l = l_of_a(a);
    const float* ap = A + (long)n*1080 + a*9 + c;
    float* qp = Q + (long)n*1080 + a*9 + c;
    float av[6], qv[6];
    #pragma unroll
    for (int s = 0; s < 6; s++) { av[s] = ap[s*180]; qv[s] = qp[s*180]; }
    #pragma unroll
    for (int s = 0; s < 6; s++) {
        float m = 0.f;
        #pragma unroll
        for (int sp = 0; sp < 6; sp++) m += av[sp] * W_mem[(l*6 + sp)*6 + s];
        qp[s*180] = qv[s] * MP_NORM + m;
    }
}

// MLP readout + per-graph segment sum. One 64-thread block per node.
__global__ __launch_bounds__(64) void k_mlp(
    const float* __restrict__ B, const float* __restrict__ B2,
    const float* __restrict__ W1, const float* __restrict__ b1,
    const float* __restrict__ W2, const float* __restrict__ b2,
    const float* __restrict__ W3, const float* __restrict__ b3,
    const int* __restrict__ batch, float* __restrict__ out)
{
    __shared__ float f[648];
    __shared__ float h1[64];
    __shared__ float h2[32];
    const int n = blockIdx.x, tid = threadIdx.x;
    const float* bp  = B  + (long)n * 324;
    const float* bp2 = B2 + (long)n * 324;
    for (int j = tid; j < 324; j += 64) {
        f[2*j]   = bp[j];
        f[2*j+1] = bp2[j];
    }
    __syncthreads();
    float h = b1[tid];
    for (int j = 0; j < 648; j++) h += f[j] * W1[j*64 + tid];
    h = h / (1.0f + expf(-h));
    h1[tid] = h;
    __syncthreads();
    if (tid < 32) {
        float g = b2[tid];
        #pragma unroll
        for (int k = 0; k < 64; k++) g += h1[k] * W2[k*32 + tid];
        g = g / (1.0f + expf(-g));
        h2[tid] = g;
    }
    __syncthreads();
    if (tid == 0) {
        float acc = b3[0];
        #pragma unroll
        for (int k = 0; k < 32; k++) acc += h2[k] * W3[k];
        atomicAdd(out + batch[n], acc);
    }
}

extern "C" void kernel_launch(void* const* d_in, const int* in_sizes, int n_in,
                              void* d_out, int out_size, void* d_ws, size_t ws_size,
                              hipStream_t stream)
{
    const float* pos    = (const float*)d_in[0];
    const int*   ntype  = (const int*)  d_in[1];
    const int*   src    = (const int*)  d_in[2];
    const int*   dst    = (const int*)  d_in[3];
    const float* shifts = (const float*)d_in[4];
    const int*   batch  = (const int*)  d_in[5];
    const float* Wemb   = (const float*)d_in[6];
    const float* freqs  = (const float*)d_in[7];
    const float* W_rt   = (const float*)d_in[8];
    const float* W_mem  = (const float*)d_in[9];
    const float* W_Ar   = (const float*)d_in[10];
    const float* W_chi  = (const float*)d_in[11];
    const float* W1     = (const float*)d_in[12];
    const float* b1     = (const float*)d_in[13];
    const float* W2     = (const float*)d_in[14];
    const float* b2     = (const float*)d_in[15];
    const float* W3     = (const float*)d_in[16];
    const float* b3     = (const float*)d_in[17];

    float* ws  = (float*)d_ws;
    float* A   = ws;                 // [NN,1080]
    float* Q   = A  + (size_t)NN * 1080;   // [NN,1080]
    float* B   = Q  + (size_t)NN * 1080;   // [NN,324]
    float* B2  = B  + (size_t)NN * 324;    // [NN,324]
    float* chi = B2 + (size_t)NN * 324;    // [NN,9]

    hipMemsetAsync(A, 0, (size_t)NN * 1080 * sizeof(float), stream);
    hipMemsetAsync(Q, 0, (size_t)NN * 1080 * sizeof(float), stream);
    hipMemsetAsync(d_out, 0, (size_t)out_size * sizeof(float), stream);

    k_edge1<<<NE/4, 256, 0, stream>>>(pos, ntype, src, dst, shifts, Wemb, freqs,
                                      W_rt, A);
    k_symm<<<(NN*54 + 255)/256, 256, 0, stream>>>(A, B);
    k_chi<<<(NN*9 + 255)/256, 256, 0, stream>>>(B, W_chi, chi);
    k_edge2<<<NE/4, 256, 0, stream>>>(pos, ntype, src, dst, shifts, Wemb, freqs,
                                      W_rt, W_Ar, chi, A, Q);
    k_comb<<<(NN*180 + 255)/256, 256, 0, stream>>>(A, W_mem, Q);
    k_symm<<<(NN*54 + 255)/256, 256, 0, stream>>>(Q, B2);
    k_mlp<<<NN, 64, 0, stream>>>(B, B2, W1, b1, W2, b2, W3, b3, batch,
                                 (float*)d_out);
}